// Round 2
// baseline (418.370 us; speedup 1.0000x reference)
//
#include <hip/hip_runtime.h>
#include <hip/hip_bf16.h>

#define N_EDGES 500000
#define N_NODES 50000
#define LN_EPS 1e-5f

typedef __attribute__((ext_vector_type(8))) short bf16x8;
typedef __attribute__((ext_vector_type(4))) float f32x4;

static __device__ __forceinline__ short f2bf(float f) {
  unsigned u = __builtin_bit_cast(unsigned, f);
  u += 0x7fffu + ((u >> 16) & 1u);  // round-to-nearest-even
  return (short)(u >> 16);
}

// Convert W1 [384,128] -> W1^T bf16 [128 n][384 k]; W2 [128,128] -> W2^T bf16 [128 n][128 k]
__global__ void convert_weights_kernel(const float* __restrict__ W1,
                                       const float* __restrict__ W2,
                                       short* __restrict__ w1t,
                                       short* __restrict__ w2t) {
  int i = blockIdx.x * blockDim.x + threadIdx.x;
  if (i < 384 * 128) {
    int n = i / 384, k = i - n * 384;
    w1t[i] = f2bf(W1[k * 128 + n]);
  }
  if (i < 128 * 128) {
    int n = i >> 7, k = i & 127;
    w2t[i] = f2bf(W2[k * 128 + n]);
  }
}

// One block = 4 waves = 128 edges. Wave w owns rows [w*32, w*32+32).
// GEMM1 (pipelined gather) -> SiLU -> H bf16 in LDS (swizzled) -> GEMM2 ->
// LayerNorm -> fp32 tile in LDS -> coalesced residual+store.
__global__ __launch_bounds__(256, 2) void edge_mlp_kernel(
    const float* __restrict__ efeat, const float* __restrict__ nfeat,
    const int* __restrict__ src, const int* __restrict__ dst,
    const short* __restrict__ w1t, const short* __restrict__ w2t,
    const float* __restrict__ b1, const float* __restrict__ b2,
    const float* __restrict__ gamma, const float* __restrict__ beta,
    float* __restrict__ out) {
  __shared__ float smem[128 * 128];  // 64 KB: first 32 KB = H bf16; later full = fp32 out tile
  short* Hlds = (short*)smem;
  char* hb = (char*)smem;

  const int tid = threadIdx.x;
  const int lane = tid & 63;
  const int wave = tid >> 6;
  const int lrow = lane & 15;   // A-frag row / C-frag col
  const int kgrp = lane >> 4;   // 0..3
  const int rbase = wave * 32;
  const int ebase = blockIdx.x * 128;

  // Per-lane row pointers for the 3 concat segments (k 0-127 / 128-255 / 256-383)
  const float* pA[2][3];
#pragma unroll
  for (int m = 0; m < 2; ++m) {
    int e = ebase + rbase + m * 16 + lrow;
    int ec = e < N_EDGES ? e : (N_EDGES - 1);
    pA[m][0] = efeat + (size_t)ec * 128;
    pA[m][1] = nfeat + (size_t)src[ec] * 128;
    pA[m][2] = nfeat + (size_t)dst[ec] * 128;
  }

  f32x4 acc[2][8];
#pragma unroll
  for (int m = 0; m < 2; ++m)
#pragma unroll
    for (int n = 0; n < 8; ++n) acc[m][n] = (f32x4)0.f;

  // ---- GEMM1: K=384, 12 k-steps grouped in 6 pairs, 2-buffer register pipeline ----
  f32x4 stg[2][2][2][2];  // [buf][m][j][half] — all indices static after unroll

  auto issue = [&](int p, int buf) {
#pragma unroll
    for (int m = 0; m < 2; ++m)
#pragma unroll
      for (int j = 0; j < 2; ++j) {
        int ks = 2 * p + j;
        const float* ptr = pA[m][ks >> 2] + (ks & 3) * 32 + kgrp * 8;
        stg[buf][m][j][0] = *(const f32x4*)ptr;
        stg[buf][m][j][1] = *(const f32x4*)(ptr + 4);
      }
  };

  issue(0, 0);
#pragma unroll
  for (int p = 0; p < 6; ++p) {
    if (p < 5) issue(p + 1, (p + 1) & 1);
#pragma unroll
    for (int j = 0; j < 2; ++j) {
      const int ks = 2 * p + j;
      bf16x8 a[2];
#pragma unroll
      for (int m = 0; m < 2; ++m) {
        f32x4 lo = stg[p & 1][m][j][0];
        f32x4 hi = stg[p & 1][m][j][1];
        bf16x8 t;
#pragma unroll
        for (int q = 0; q < 4; ++q) { t[q] = f2bf(lo[q]); t[4 + q] = f2bf(hi[q]); }
        a[m] = t;
      }
      const int k0 = ks * 32 + kgrp * 8;
#pragma unroll
      for (int n = 0; n < 8; ++n) {
        bf16x8 b = *(const bf16x8*)(w1t + (n * 16 + lrow) * 384 + k0);
        acc[0][n] = __builtin_amdgcn_mfma_f32_16x16x32_bf16(a[0], b, acc[0][n], 0, 0, 0);
        acc[1][n] = __builtin_amdgcn_mfma_f32_16x16x32_bf16(a[1], b, acc[1][n], 0, 0, 0);
      }
    }
  }

  // ---- bias1 + SiLU -> LDS (bf16, XOR swizzle byte^=(row&7)<<4) ----
  float b1v[8];
#pragma unroll
  for (int n = 0; n < 8; ++n) b1v[n] = b1[n * 16 + lrow];

#pragma unroll
  for (int m = 0; m < 2; ++m)
#pragma unroll
    for (int n = 0; n < 8; ++n)
#pragma unroll
      for (int r = 0; r < 4; ++r) {
        float x = acc[m][n][r] + b1v[n];
        float h = x / (1.f + __expf(-x));  // SiLU
        int row = rbase + m * 16 + kgrp * 4 + r;  // C/D: row=(lane>>4)*4+reg
        int col = n * 16 + lrow;                  // C/D: col=lane&15
        int byte = ((row << 8) + (col << 1)) ^ ((row & 7) << 4);
        *(short*)(hb + byte) = f2bf(h);
      }
  __syncthreads();

  // ---- GEMM2: K=128, 4 k-steps, A from LDS ----
  f32x4 acc2[2][8];
#pragma unroll
  for (int m = 0; m < 2; ++m)
#pragma unroll
    for (int n = 0; n < 8; ++n) acc2[m][n] = (f32x4)0.f;

#pragma unroll
  for (int ks = 0; ks < 4; ++ks) {
    bf16x8 a2[2];
#pragma unroll
    for (int m = 0; m < 2; ++m) {
      int row = rbase + m * 16 + lrow;
      int byte = ((row << 8) + ((ks * 32 + kgrp * 8) << 1)) ^ ((row & 7) << 4);
      a2[m] = *(const bf16x8*)(hb + byte);
    }
#pragma unroll
    for (int n = 0; n < 8; ++n) {
      bf16x8 b = *(const bf16x8*)(w2t + (n * 16 + lrow) * 128 + ks * 32 + kgrp * 8);
#pragma unroll
      for (int m = 0; m < 2; ++m)
        acc2[m][n] = __builtin_amdgcn_mfma_f32_16x16x32_bf16(a2[m], b, acc2[m][n], 0, 0, 0);
    }
  }

  // ---- bias2 + LayerNorm stats (16-lane group reduce) ----
  float b2v[8], gv[8], bev[8];
#pragma unroll
  for (int n = 0; n < 8; ++n) {
    int c = n * 16 + lrow;
    b2v[n] = b2[c];
    gv[n] = gamma[c];
    bev[n] = beta[c];
  }

  __syncthreads();  // all H reads done — smem will be overwritten with fp32 out tile

#pragma unroll
  for (int m = 0; m < 2; ++m) {
    float s1[4], s2[4];
#pragma unroll
    for (int r = 0; r < 4; ++r) { s1[r] = 0.f; s2[r] = 0.f; }
#pragma unroll
    for (int n = 0; n < 8; ++n)
#pragma unroll
      for (int r = 0; r < 4; ++r) {
        float x = acc2[m][n][r] + b2v[n];
        s1[r] += x;
        s2[r] += x * x;
      }
#pragma unroll
    for (int off = 1; off < 16; off <<= 1)
#pragma unroll
      for (int r = 0; r < 4; ++r) {
        s1[r] += __shfl_xor(s1[r], off, 64);
        s2[r] += __shfl_xor(s2[r], off, 64);
      }
#pragma unroll
    for (int r = 0; r < 4; ++r) {
      float mu = s1[r] * (1.f / 128.f);
      float var = s2[r] * (1.f / 128.f) - mu * mu;
      float rs = rsqrtf(var + LN_EPS);
      int row = rbase + m * 16 + kgrp * 4 + r;
#pragma unroll
      for (int n = 0; n < 8; ++n) {
        float x = acc2[m][n][r] + b2v[n];
        smem[row * 128 + n * 16 + lrow] = (x - mu) * rs * gv[n] + bev[n];
      }
    }
  }
  __syncthreads();

  // ---- coalesced residual + store: 128 rows x 32 float4 ----
  const f32x4* olds = (const f32x4*)smem;
#pragma unroll
  for (int it = 0; it < 16; ++it) {
    int idx = it * 256 + tid;
    int row = idx >> 5;
    int c4 = idx & 31;
    int e = ebase + row;
    if (e < N_EDGES) {
      f32x4 o = olds[idx];
      f32x4 ef = *(const f32x4*)(efeat + (size_t)e * 128 + c4 * 4);
      o += ef;
      *(f32x4*)(out + (size_t)e * 128 + c4 * 4) = o;
    }
  }
}

extern "C" void kernel_launch(void* const* d_in, const int* in_sizes, int n_in,
                              void* d_out, int out_size, void* d_ws, size_t ws_size,
                              hipStream_t stream) {
  const float* efeat = (const float*)d_in[0];
  const float* nfeat = (const float*)d_in[1];
  const int* src = (const int*)d_in[2];
  const int* dst = (const int*)d_in[3];
  const float* W1 = (const float*)d_in[4];
  const float* b1 = (const float*)d_in[5];
  const float* W2 = (const float*)d_in[6];
  const float* b2 = (const float*)d_in[7];
  const float* gamma = (const float*)d_in[8];
  const float* beta = (const float*)d_in[9];
  float* out = (float*)d_out;

  short* w1t = (short*)d_ws;              // 384*128 bf16 = 96 KB
  short* w2t = w1t + 384 * 128;           // 128*128 bf16 = 32 KB

  // nfeat passthrough (second tuple element)
  hipMemcpyAsync(out + (size_t)N_EDGES * 128, nfeat,
                 (size_t)N_NODES * 128 * sizeof(float),
                 hipMemcpyDeviceToDevice, stream);

  convert_weights_kernel<<<192, 256, 0, stream>>>(W1, W2, w1t, w2t);

  const int nblocks = (N_EDGES + 127) / 128;  // 3907
  edge_mlp_kernel<<<nblocks, 256, 0, stream>>>(efeat, nfeat, src, dst, w1t, w2t,
                                               b1, b2, gamma, beta, out);
}

// Round 3
// 412.581 us; speedup vs baseline: 1.0140x; 1.0140x over previous
//
#include <hip/hip_runtime.h>
#include <hip/hip_bf16.h>

#define N_EDGES 500000
#define N_NODES 50000
#define LN_EPS 1e-5f

typedef __attribute__((ext_vector_type(8))) short bf16x8;
typedef __attribute__((ext_vector_type(4))) float f32x4;

// Proper cast so the compiler can fuse pairs into v_cvt_pk_bf16_f32 (T12/m240).
static __device__ __forceinline__ short f2bf(float f) {
  return __builtin_bit_cast(short, __float2bfloat16(f));
}
static __device__ __forceinline__ float bf2f(short s) {
  unsigned u = ((unsigned)(unsigned short)s) << 16;
  return __builtin_bit_cast(float, u);
}

// Convert W1 [384,128] -> W1^T bf16 [128 n][384 k]; W2 [128,128] -> W2^T bf16 [128 n][128 k]
__global__ void convert_weights_kernel(const float* __restrict__ W1,
                                       const float* __restrict__ W2,
                                       short* __restrict__ w1t,
                                       short* __restrict__ w2t) {
  int i = blockIdx.x * blockDim.x + threadIdx.x;
  if (i < 384 * 128) {
    int n = i / 384, k = i - n * 384;
    w1t[i] = f2bf(W1[k * 128 + n]);
  }
  if (i < 128 * 128) {
    int n = i >> 7, k = i & 127;
    w2t[i] = f2bf(W2[k * 128 + n]);
  }
}

// One block = 4 waves = 128 edges. Wave w owns rows [w*32, w*32+32).
// GEMM1 (pipelined gather, cvt_pk bf16) -> SiLU -> H bf16 LDS (XOR swizzle)
// -> GEMM2 -> LayerNorm -> bf16 out tile in SAME 32KB LDS -> coalesced
// fp32 residual+store.
__global__ __launch_bounds__(256, 3) void edge_mlp_kernel(
    const float* __restrict__ efeat, const float* __restrict__ nfeat,
    const int* __restrict__ src, const int* __restrict__ dst,
    const short* __restrict__ w1t, const short* __restrict__ w2t,
    const float* __restrict__ b1, const float* __restrict__ b2,
    const float* __restrict__ gamma, const float* __restrict__ beta,
    float* __restrict__ out) {
  __shared__ short Hlds[128 * 128];  // 32 KB bf16, XOR-swizzled rows
  char* hb = (char*)Hlds;

  const int tid = threadIdx.x;
  const int lane = tid & 63;
  const int wave = tid >> 6;
  const int lrow = lane & 15;   // A-frag row / C-frag col
  const int kgrp = lane >> 4;   // 0..3
  const int rbase = wave * 32;
  const int ebase = blockIdx.x * 128;

  // Per-lane row pointers for the 3 concat segments (k 0-127 / 128-255 / 256-383)
  const float* pA[2][3];
#pragma unroll
  for (int m = 0; m < 2; ++m) {
    int e = ebase + rbase + m * 16 + lrow;
    int ec = e < N_EDGES ? e : (N_EDGES - 1);
    pA[m][0] = efeat + (size_t)ec * 128;
    pA[m][1] = nfeat + (size_t)src[ec] * 128;
    pA[m][2] = nfeat + (size_t)dst[ec] * 128;
  }

  f32x4 acc[2][8];
#pragma unroll
  for (int m = 0; m < 2; ++m)
#pragma unroll
    for (int n = 0; n < 8; ++n) acc[m][n] = (f32x4)0.f;

  // ---- GEMM1: K=384, 12 k-steps in 6 pairs, 2-buffer register pipeline ----
  f32x4 stg[2][2][2][2];  // [buf][m][j][half] — all indices static after unroll

  auto issue = [&](int p, int buf) {
#pragma unroll
    for (int m = 0; m < 2; ++m)
#pragma unroll
      for (int j = 0; j < 2; ++j) {
        int ks = 2 * p + j;
        const float* ptr = pA[m][ks >> 2] + (ks & 3) * 32 + kgrp * 8;
        stg[buf][m][j][0] = *(const f32x4*)ptr;
        stg[buf][m][j][1] = *(const f32x4*)(ptr + 4);
      }
  };

  issue(0, 0);
#pragma unroll
  for (int p = 0; p < 6; ++p) {
    if (p < 5) issue(p + 1, (p + 1) & 1);
#pragma unroll
    for (int j = 0; j < 2; ++j) {
      const int ks = 2 * p + j;
      bf16x8 a[2];
#pragma unroll
      for (int m = 0; m < 2; ++m) {
        f32x4 lo = stg[p & 1][m][j][0];
        f32x4 hi = stg[p & 1][m][j][1];
        bf16x8 t;
#pragma unroll
        for (int q = 0; q < 4; ++q) { t[q] = f2bf(lo[q]); t[4 + q] = f2bf(hi[q]); }
        a[m] = t;
      }
      const int k0 = ks * 32 + kgrp * 8;
#pragma unroll
      for (int n = 0; n < 8; ++n) {
        bf16x8 b = *(const bf16x8*)(w1t + (n * 16 + lrow) * 384 + k0);
        acc[0][n] = __builtin_amdgcn_mfma_f32_16x16x32_bf16(a[0], b, acc[0][n], 0, 0, 0);
        acc[1][n] = __builtin_amdgcn_mfma_f32_16x16x32_bf16(a[1], b, acc[1][n], 0, 0, 0);
      }
    }
  }

  // ---- bias1 + SiLU -> LDS (bf16, XOR swizzle byte^=(row&7)<<4) ----
  float b1v[8];
#pragma unroll
  for (int n = 0; n < 8; ++n) b1v[n] = b1[n * 16 + lrow];

#pragma unroll
  for (int m = 0; m < 2; ++m)
#pragma unroll
    for (int n = 0; n < 8; ++n)
#pragma unroll
      for (int r = 0; r < 4; ++r) {
        float x = acc[m][n][r] + b1v[n];
        float h = x / (1.f + __expf(-x));  // SiLU
        int row = rbase + m * 16 + kgrp * 4 + r;  // C/D: row=(lane>>4)*4+reg
        int col = n * 16 + lrow;                  // C/D: col=lane&15
        int byte = ((row << 8) + (col << 1)) ^ ((row & 7) << 4);
        *(short*)(hb + byte) = f2bf(h);
      }
  __syncthreads();

  // ---- GEMM2: K=128, 4 k-steps, A from LDS ----
  f32x4 acc2[2][8];
#pragma unroll
  for (int m = 0; m < 2; ++m)
#pragma unroll
    for (int n = 0; n < 8; ++n) acc2[m][n] = (f32x4)0.f;

#pragma unroll
  for (int ks = 0; ks < 4; ++ks) {
    bf16x8 a2[2];
#pragma unroll
    for (int m = 0; m < 2; ++m) {
      int row = rbase + m * 16 + lrow;
      int byte = ((row << 8) + ((ks * 32 + kgrp * 8) << 1)) ^ ((row & 7) << 4);
      a2[m] = *(const bf16x8*)(hb + byte);
    }
#pragma unroll
    for (int n = 0; n < 8; ++n) {
      bf16x8 b = *(const bf16x8*)(w2t + (n * 16 + lrow) * 128 + ks * 32 + kgrp * 8);
#pragma unroll
      for (int m = 0; m < 2; ++m)
        acc2[m][n] = __builtin_amdgcn_mfma_f32_16x16x32_bf16(a2[m], b, acc2[m][n], 0, 0, 0);
    }
  }

  __syncthreads();  // all H reads done — LDS will be overwritten with bf16 out tile

  // ---- bias2 + LayerNorm (16-lane group reduce) -> bf16 out tile in LDS ----
  float b2v[8], gv[8], bev[8];
#pragma unroll
  for (int n = 0; n < 8; ++n) {
    int c = n * 16 + lrow;
    b2v[n] = b2[c];
    gv[n] = gamma[c];
    bev[n] = beta[c];
  }

#pragma unroll
  for (int m = 0; m < 2; ++m) {
    float s1[4], s2[4];
#pragma unroll
    for (int r = 0; r < 4; ++r) { s1[r] = 0.f; s2[r] = 0.f; }
#pragma unroll
    for (int n = 0; n < 8; ++n)
#pragma unroll
      for (int r = 0; r < 4; ++r) {
        float x = acc2[m][n][r] + b2v[n];
        s1[r] += x;
        s2[r] += x * x;
      }
#pragma unroll
    for (int off = 1; off < 16; off <<= 1)
#pragma unroll
      for (int r = 0; r < 4; ++r) {
        s1[r] += __shfl_xor(s1[r], off, 64);
        s2[r] += __shfl_xor(s2[r], off, 64);
      }
#pragma unroll
    for (int r = 0; r < 4; ++r) {
      float mu = s1[r] * (1.f / 128.f);
      float var = s2[r] * (1.f / 128.f) - mu * mu;
      float rs = rsqrtf(var + LN_EPS);
      int row = rbase + m * 16 + kgrp * 4 + r;
#pragma unroll
      for (int n = 0; n < 8; ++n) {
        float x = acc2[m][n][r] + b2v[n];
        float y = (x - mu) * rs * gv[n] + bev[n];
        int col = n * 16 + lrow;
        int byte = ((row << 8) + (col << 1)) ^ ((row & 7) << 4);
        *(short*)(hb + byte) = f2bf(y);
      }
    }
  }
  __syncthreads();

  // ---- coalesced flush: read bf16 tile, +efeat (fp32), store fp32 ----
  // 128 rows x 16 chunks of 8 cols = 2048 chunks / 256 threads = 8 iters
#pragma unroll
  for (int it = 0; it < 8; ++it) {
    int idx = it * 256 + tid;
    int row = idx >> 4;
    int c8 = (idx & 15) * 8;
    int e = ebase + row;
    if (e < N_EDGES) {
      int byte = ((row << 8) + (c8 << 1)) ^ ((row & 7) << 4);
      bf16x8 v = *(const bf16x8*)(hb + byte);
      const float* er = efeat + (size_t)e * 128 + c8;
      float* orow = out + (size_t)e * 128 + c8;
      f32x4 lo = *(const f32x4*)er;
      f32x4 hi = *(const f32x4*)(er + 4);
      f32x4 o0, o1;
#pragma unroll
      for (int q = 0; q < 4; ++q) {
        o0[q] = bf2f(v[q]) + lo[q];
        o1[q] = bf2f(v[4 + q]) + hi[q];
      }
      *(f32x4*)orow = o0;
      *(f32x4*)(orow + 4) = o1;
    }
  }
}

extern "C" void kernel_launch(void* const* d_in, const int* in_sizes, int n_in,
                              void* d_out, int out_size, void* d_ws, size_t ws_size,
                              hipStream_t stream) {
  const float* efeat = (const float*)d_in[0];
  const float* nfeat = (const float*)d_in[1];
  const int* src = (const int*)d_in[2];
  const int* dst = (const int*)d_in[3];
  const float* W1 = (const float*)d_in[4];
  const float* b1 = (const float*)d_in[5];
  const float* W2 = (const float*)d_in[6];
  const float* b2 = (const float*)d_in[7];
  const float* gamma = (const float*)d_in[8];
  const float* beta = (const float*)d_in[9];
  float* out = (float*)d_out;

  short* w1t = (short*)d_ws;              // 384*128 bf16 = 96 KB
  short* w2t = w1t + 384 * 128;           // 128*128 bf16 = 32 KB

  // nfeat passthrough (second tuple element)
  hipMemcpyAsync(out + (size_t)N_EDGES * 128, nfeat,
                 (size_t)N_NODES * 128 * sizeof(float),
                 hipMemcpyDeviceToDevice, stream);

  convert_weights_kernel<<<192, 256, 0, stream>>>(W1, W2, w1t, w2t);

  const int nblocks = (N_EDGES + 127) / 128;  // 3907
  edge_mlp_kernel<<<nblocks, 256, 0, stream>>>(efeat, nfeat, src, dst, w1t, w2t,
                                               b1, b2, gamma, beta, out);
}